// Round 6
// baseline (697.454 us; speedup 1.0000x reference)
//
#include <hip/hip_runtime.h>

// lstm_seq2seq fused persistent kernel for MI355X (gfx950), R6.
// R5 structure (256 WGs x 512 thr x 64 rows, 1 WG/CU, A=weights from L2,
// B=h in LDS double-buffer, c in regs, decoder feedback folded) plus:
//  - log2e folded into weight rows (sigmoid x1.4427, g-gate x2.8854) -> raw
//    v_exp_f32, no pre-multiplies in the elementwise phase
//  - kt=0 MFMA takes literal-zero C -> no 128x accvgpr zero-init per step
//  - kt=8 (aug: x + bias) weight slice staged in LDS (64 KB) -> 11% less L2
//    stream; restaged at the two phase boundaries
//  - gate clamps dropped (exp2 is overflow-graceful); single med3 clamp on c

#define SEQ  20
#define TLEN 30
#define LOG2E  1.442695041f
#define LOG2E2 2.885390082f

typedef _Float16 half8   __attribute__((ext_vector_type(8)));
typedef _Float16 half4   __attribute__((ext_vector_type(4)));
typedef float    floatx4 __attribute__((ext_vector_type(4)));

// Packed weights. Gate row n (0..1023), k (0..287):
//   g=n>>8, c=(n>>4)&15, l16=n&15, w=c>>1, cc=c&1, i=cc*4+g,
//   kt=k>>5, q=(k>>3)&3, j=k&7
//   dst = ((w*9+kt)*8 + i)*512 + q*128 + l16*8 + j
__device__ _Float16 g_w_enc[1024 * 288];
__device__ _Float16 g_w_dec0[1024 * 288];
__device__ _Float16 g_w_deff[1024 * 288];
__device__ _Float16 g_wout[512];           // W_out [2][256] f16 (unscaled)

__global__ void prep_kernel(const float* __restrict__ W_emb,
                            const float* __restrict__ b_emb,
                            const float* __restrict__ W_ih_enc,
                            const float* __restrict__ W_hh_enc,
                            const float* __restrict__ b_enc,
                            const float* __restrict__ W_ih_dec,
                            const float* __restrict__ W_hh_dec,
                            const float* __restrict__ b_dec,
                            const float* __restrict__ W_out,
                            const float* __restrict__ b_out) {
    int gid = blockIdx.x * blockDim.x + threadIdx.x;
    int stride = gridDim.x * blockDim.x;
    for (int s = gid; s < 1024 * 288; s += stride) {
        int n = s / 288, k = s - n * 288;
        int g = n >> 8, c = (n >> 4) & 15, l16 = n & 15;
        int w = c >> 1, cc = c & 1;
        int i = cc * 4 + g;
        int kt = k >> 5, q = (k >> 3) & 3, j = k & 7;
        int dst = ((w * 9 + kt) * 8 + i) * 512 + q * 128 + l16 * 8 + j;
        float sc = (g == 2) ? LOG2E2 : LOG2E;   // exp2-folded row scale
        float fe = 0.f, fd = 0.f, ff = 0.f;
        if (k < 256) {
            fe = W_hh_enc[n * 256 + k];
            fd = W_hh_dec[n * 256 + k];
            ff = fd + W_ih_dec[2 * n] * W_out[k]
                    + W_ih_dec[2 * n + 1] * W_out[256 + k];
        } else {
            int kp = k - 256;
            if (kp < 2) {
                fd = W_ih_dec[2 * n + kp];
                const float* wr = &W_ih_enc[n * 64];
                for (int e = 0; e < 64; e++) fe = fmaf(wr[e], W_emb[2 * e + kp], fe);
            } else if (kp == 2) {
                fd = b_dec[n];
                ff = b_dec[n] + W_ih_dec[2 * n] * b_out[0]
                              + W_ih_dec[2 * n + 1] * b_out[1];
                fe = b_enc[n];
                const float* wr = &W_ih_enc[n * 64];
                for (int e = 0; e < 64; e++) fe = fmaf(wr[e], b_emb[e], fe);
            }
        }
        g_w_enc[dst]  = (_Float16)(fe * sc);
        g_w_dec0[dst] = (_Float16)(fd * sc);
        g_w_deff[dst] = (_Float16)(ff * sc);
    }
    if (gid < 512) g_wout[gid] = (_Float16)W_out[gid];
}

__global__ __launch_bounds__(512, 2) void lstm_fused(
        const float* __restrict__ x_input,    // [20][16384][2]
        const float* __restrict__ b_out,      // [2]
        float* __restrict__ out)              // [30][16384][2]
{
    __shared__ __align__(16) _Float16 h_pack[2][18432];        // 73728 B
    __shared__ __align__(16) _Float16 w8_lds[8 * 4096];        // 65536 B (kt=8 slices)
    __shared__ __align__(16) float    partial_lds[2][8 * 132]; // 8448 B

    const int tid = threadIdx.x;
    const int w   = tid >> 6;
    const int L   = tid & 63;
    const int l16 = L & 15;
    const int q   = L >> 4;
    const long row0 = (long)blockIdx.x * 64;

    // stage a matrix's kt=8 slices (8 waves x 4096 halves) into LDS
    auto stage_w8 = [&](const _Float16* __restrict__ gsrc) {
        int4* dst = (int4*)w8_lds;
        for (int i4 = tid; i4 < 4096; i4 += 512) {
            int wv = i4 >> 9, rest = i4 & 511;
            dst[i4] = *(const int4*)&gsrc[(wv * 9 + 8) * 4096 + rest * 8];
        }
    };

    // ---- init ----
    {
        int* hz = (int*)&h_pack[0][0];
        for (int idx = tid; idx < 18432; idx += 512) hz[idx] = 0;  // both bufs
        stage_w8(g_w_enc);
    }
    __syncthreads();
    if (tid < 128) {   // "1" column, both buffers, never overwritten
        int buf = tid >> 6, b = tid & 63;
        h_pack[buf][((b >> 4) * 9 + 8) * 512 + (b & 15) * 8 + 2] = (_Float16)1.f;
    }
    if (tid < 128) {   // x(0) into buf0
        int b = tid >> 1, jj = tid & 1;
        h_pack[0][((b >> 4) * 9 + 8) * 512 + (b & 15) * 8 + jj] =
            (_Float16)x_input[(row0 + b) * 2 + jj];
    }

    const float bo = b_out[tid & 1];
    const int aoff = q * 128 + l16 * 8;
    const _Float16* __restrict__ wenc_w  = &g_w_enc[w * 36864];
    const _Float16* __restrict__ wdec0_w = &g_w_dec0[w * 36864];
    const _Float16* __restrict__ wdeff_w = &g_w_deff[w * 36864];

    _Float16 wo[2][2][4];   // [jj][cc][r] for cells 32w+16cc+4q+r
#pragma unroll
    for (int jj = 0; jj < 2; jj++)
#pragma unroll
        for (int cc = 0; cc < 2; cc++)
#pragma unroll
            for (int r = 0; r < 4; r++)
                wo[jj][cc][r] = g_wout[jj * 256 + 32 * w + 16 * cc + 4 * q + r];

    floatx4 acc[8][4];
    float   c_st[4][2][4];
#pragma unroll
    for (int nt = 0; nt < 4; nt++)
#pragma unroll
        for (int cc = 0; cc < 2; cc++)
#pragma unroll
            for (int r = 0; r < 4; r++) c_st[nt][cc][r] = 0.f;

    __syncthreads();

    int cur = 0;
#pragma unroll 1
    for (int t = 0; t < SEQ + TLEN; t++) {
        const _Float16* __restrict__ Wb =
            (t < SEQ) ? wenc_w : (t == SEQ) ? wdec0_w : wdeff_w;
        const _Float16* __restrict__ hp = h_pack[cur];
        _Float16* __restrict__ hn = h_pack[cur ^ 1];

        // ---- gates = [h|x|1] @ Waug^T ; kt=0 takes literal-zero C ----
#pragma unroll
        for (int kt = 0; kt < 9; kt++) {
            half8 B[4];
#pragma unroll
            for (int nt = 0; nt < 4; nt++)
                B[nt] = *(const half8*)&hp[(nt * 9 + kt) * 512 + aoff];
#pragma unroll
            for (int i = 0; i < 8; i++) {
                half8 Aw = (kt < 8)
                    ? *(const half8*)&Wb[(kt * 8 + i) * 512 + aoff]
                    : *(const half8*)&w8_lds[w * 4096 + i * 512 + aoff];
                if (kt == 0) {
#pragma unroll
                    for (int nt = 0; nt < 4; nt++)
                        acc[i][nt] = __builtin_amdgcn_mfma_f32_16x16x32_f16(
                            Aw, B[nt], (floatx4)(0.f), 0, 0, 0);
                } else {
#pragma unroll
                    for (int nt = 0; nt < 4; nt++)
                        acc[i][nt] = __builtin_amdgcn_mfma_f32_16x16x32_f16(
                            Aw, B[nt], acc[i][nt], 0, 0, 0);
                }
            }
        }

        float xval = 0.f;
        if (t < SEQ && tid < 128) {
            int srct = (t + 1 < SEQ) ? t + 1 : SEQ - 1;
            xval = x_input[(long)srct * 32768 + (row0 + (tid >> 1)) * 2 + (tid & 1)];
        }

        // ---- elementwise LSTM (preacts pre-scaled by log2e / 2log2e) ----
        const bool dec = (t >= SEQ);
        float po[4][2];
#pragma unroll
        for (int nt = 0; nt < 4; nt++) { po[nt][0] = 0.f; po[nt][1] = 0.f; }

#pragma unroll
        for (int nt = 0; nt < 4; nt++)
#pragma unroll
            for (int cc = 0; cc < 2; cc++) {
                half4 hv4;
                float hvf[4];
#pragma unroll
                for (int r = 0; r < 4; r++) {
                    float ai = acc[cc * 4 + 0][nt][r];
                    float af = acc[cc * 4 + 1][nt][r];
                    float ag = acc[cc * 4 + 2][nt][r];
                    float ao = acc[cc * 4 + 3][nt][r];
                    float eI = __builtin_amdgcn_exp2f(-ai);
                    float eG = __builtin_amdgcn_exp2f(-ag);
                    float eF = __builtin_amdgcn_exp2f(-af);
                    float eO = __builtin_amdgcn_exp2f(-ao);
                    float ig = (1.f - eG) *
                        __builtin_amdgcn_rcpf((1.f + eI) * (1.f + eG));
                    float fs = __builtin_amdgcn_rcpf(1.f + eF);
                    float cn = fmaf(fs, c_st[nt][cc][r], ig);
                    c_st[nt][cc][r] = cn;
                    float cnc = fminf(fmaxf(cn, -12.f), 12.f);
                    float eC = __builtin_amdgcn_exp2f(-LOG2E2 * cnc);
                    float hv = (1.f - eC) *
                        __builtin_amdgcn_rcpf((1.f + eO) * (1.f + eC));
                    hvf[r] = hv;
                    hv4[r] = (_Float16)hv;
                }
                *(half4*)&hn[(nt * 9 + w) * 512 + (2 * cc + (q >> 1)) * 128 +
                             l16 * 8 + 4 * (q & 1)] = hv4;
                if (dec) {
#pragma unroll
                    for (int r = 0; r < 4; r++) {
                        po[nt][0] = fmaf(hvf[r], (float)wo[0][cc][r], po[nt][0]);
                        po[nt][1] = fmaf(hvf[r], (float)wo[1][cc][r], po[nt][1]);
                    }
                }
            }

        if (dec) {
#pragma unroll
            for (int nt = 0; nt < 4; nt++)
#pragma unroll
                for (int jj = 0; jj < 2; jj++) {
                    float s = po[nt][jj];
                    s += __shfl_xor(s, 16);
                    s += __shfl_xor(s, 32);
                    po[nt][jj] = s;
                }
            if (q == 0) {
                float* pl = &partial_lds[t & 1][w * 132];
#pragma unroll
                for (int nt = 0; nt < 4; nt++) {
                    pl[nt * 16 + l16]      = po[nt][0];
                    pl[66 + nt * 16 + l16] = po[nt][1];
                }
            }
        }

        if (t < SEQ && tid < 128) {
            int b = tid >> 1, jj = tid & 1;
            hn[((b >> 4) * 9 + 8) * 512 + (b & 15) * 8 + jj] = (_Float16)xval;
        }

        __syncthreads();   // hn + partials complete

        // phase-boundary kt=8 restage (uniform, 2 of 50 steps)
        if (t == SEQ - 1) { stage_w8(g_w_dec0); __syncthreads(); }
        else if (t == SEQ) { stage_w8(g_w_deff); __syncthreads(); }

        if (dec && tid < 128) {
            int m = tid >> 1, jj = tid & 1;
            const float* pl = &partial_lds[t & 1][jj * 66 + m];
            float s = bo;
#pragma unroll
            for (int w8 = 0; w8 < 8; w8++) s += pl[w8 * 132];
            out[(long)(t - SEQ) * 32768 + (row0 + m) * 2 + jj] = s;
        }

        cur ^= 1;
    }
}

extern "C" void kernel_launch(void* const* d_in, const int* in_sizes, int n_in,
                              void* d_out, int out_size, void* d_ws, size_t ws_size,
                              hipStream_t stream) {
    (void)in_sizes; (void)n_in; (void)d_ws; (void)ws_size; (void)out_size;
    const float* x      = (const float*)d_in[0];
    const float* W_emb  = (const float*)d_in[1];
    const float* b_emb  = (const float*)d_in[2];
    const float* W_ih_e = (const float*)d_in[3];
    const float* W_hh_e = (const float*)d_in[4];
    const float* b_enc  = (const float*)d_in[5];
    const float* W_ih_d = (const float*)d_in[6];
    const float* W_hh_d = (const float*)d_in[7];
    const float* b_dec  = (const float*)d_in[8];
    const float* W_out  = (const float*)d_in[9];
    const float* b_out  = (const float*)d_in[10];
    float* outp = (float*)d_out;

    prep_kernel<<<512, 256, 0, stream>>>(W_emb, b_emb, W_ih_e, W_hh_e, b_enc,
                                         W_ih_d, W_hh_d, b_dec, W_out, b_out);
    lstm_fused<<<256, 512, 0, stream>>>(x, b_out, outp);
}

// Round 8
// 587.273 us; speedup vs baseline: 1.1876x; 1.1876x over previous
//
#include <hip/hip_runtime.h>

// lstm_seq2seq fused persistent kernel for MI355X (gfx950), R8.
// = R5 structure (256 WGs x 512 thr x 64 rows, 1 WG/CU; A=weights streamed
// from L2 in wave-contiguous packing, B=h in LDS double-buffer; c-state in
// regs; decoder feedback folded into weights; K=288 augmented, "1" column
// carries bias) + the two changes R6 verified as wins:
//   - log2e folded into weight rows (sigmoid x1.4427, g-gate x2.8854) ->
//     raw v_exp_f32 in the EW phase (-3.1k VALU cyc/step measured)
//   - kt=0 MFMA takes literal-zero C -> no accvgpr zero-init per step
// R6's static kt=8 LDS staging (+5.5k stall) and R7's global_load_lds
// prefetch (GPU fault) are both reverted.

#define SEQ  20
#define TLEN 30
#define LOG2E  1.442695041f
#define LOG2E2 2.885390082f

typedef _Float16 half8   __attribute__((ext_vector_type(8)));
typedef _Float16 half4   __attribute__((ext_vector_type(4)));
typedef float    floatx4 __attribute__((ext_vector_type(4)));

// Packed weights. Gate row n (0..1023), k (0..287):
//   g=n>>8, c=(n>>4)&15, l16=n&15, w=c>>1, cc=c&1, i=cc*4+g,
//   kt=k>>5, q=(k>>3)&3, j=k&7
//   dst = ((w*9+kt)*8 + i)*512 + q*128 + l16*8 + j
// => per (wave,kt): 8 contiguous 1KB A-fragments (8KB block).
__device__ _Float16 g_w_enc[1024 * 288];
__device__ _Float16 g_w_dec0[1024 * 288];
__device__ _Float16 g_w_deff[1024 * 288];
__device__ _Float16 g_wout[512];           // W_out [2][256] f16 (unscaled)

__global__ void prep_kernel(const float* __restrict__ W_emb,
                            const float* __restrict__ b_emb,
                            const float* __restrict__ W_ih_enc,
                            const float* __restrict__ W_hh_enc,
                            const float* __restrict__ b_enc,
                            const float* __restrict__ W_ih_dec,
                            const float* __restrict__ W_hh_dec,
                            const float* __restrict__ b_dec,
                            const float* __restrict__ W_out,
                            const float* __restrict__ b_out) {
    int gid = blockIdx.x * blockDim.x + threadIdx.x;
    int stride = gridDim.x * blockDim.x;
    for (int s = gid; s < 1024 * 288; s += stride) {
        int n = s / 288, k = s - n * 288;
        int g = n >> 8, c = (n >> 4) & 15, l16 = n & 15;
        int w = c >> 1, cc = c & 1;
        int i = cc * 4 + g;
        int kt = k >> 5, q = (k >> 3) & 3, j = k & 7;
        int dst = ((w * 9 + kt) * 8 + i) * 512 + q * 128 + l16 * 8 + j;
        float sc = (g == 2) ? LOG2E2 : LOG2E;   // exp2-folded row scale
        float fe = 0.f, fd = 0.f, ff = 0.f;
        if (k < 256) {
            fe = W_hh_enc[n * 256 + k];
            fd = W_hh_dec[n * 256 + k];
            ff = fd + W_ih_dec[2 * n] * W_out[k]
                    + W_ih_dec[2 * n + 1] * W_out[256 + k];
        } else {
            int kp = k - 256;
            if (kp < 2) {
                fd = W_ih_dec[2 * n + kp];
                const float* wr = &W_ih_enc[n * 64];
                for (int e = 0; e < 64; e++) fe = fmaf(wr[e], W_emb[2 * e + kp], fe);
            } else if (kp == 2) {
                fd = b_dec[n];
                ff = b_dec[n] + W_ih_dec[2 * n] * b_out[0]
                              + W_ih_dec[2 * n + 1] * b_out[1];
                fe = b_enc[n];
                const float* wr = &W_ih_enc[n * 64];
                for (int e = 0; e < 64; e++) fe = fmaf(wr[e], b_emb[e], fe);
            }
        }
        g_w_enc[dst]  = (_Float16)(fe * sc);
        g_w_dec0[dst] = (_Float16)(fd * sc);
        g_w_deff[dst] = (_Float16)(ff * sc);
    }
    if (gid < 512) g_wout[gid] = (_Float16)W_out[gid];
}

__global__ __launch_bounds__(512, 2) void lstm_fused(
        const float* __restrict__ x_input,    // [20][16384][2]
        const float* __restrict__ b_out,      // [2]
        float* __restrict__ out)              // [30][16384][2]
{
    __shared__ __align__(16) _Float16 h_pack[2][18432];        // 73728 B
    __shared__ __align__(16) float    partial_lds[2][8 * 132]; // 8448 B

    const int tid = threadIdx.x;
    const int w   = tid >> 6;
    const int L   = tid & 63;
    const int l16 = L & 15;
    const int q   = L >> 4;
    const long row0 = (long)blockIdx.x * 64;

    // ---- init ----
    {
        int* hz = (int*)&h_pack[0][0];
        for (int idx = tid; idx < 18432; idx += 512) hz[idx] = 0;  // both bufs
    }
    __syncthreads();
    if (tid < 128) {   // "1" column, both buffers, never overwritten
        int buf = tid >> 6, b = tid & 63;
        h_pack[buf][((b >> 4) * 9 + 8) * 512 + (b & 15) * 8 + 2] = (_Float16)1.f;
    }
    if (tid < 128) {   // x(0) into buf0
        int b = tid >> 1, jj = tid & 1;
        h_pack[0][((b >> 4) * 9 + 8) * 512 + (b & 15) * 8 + jj] =
            (_Float16)x_input[(row0 + b) * 2 + jj];
    }

    const float bo = b_out[tid & 1];
    const int aoff = q * 128 + l16 * 8;
    const _Float16* __restrict__ wenc_w  = &g_w_enc[w * 36864];
    const _Float16* __restrict__ wdec0_w = &g_w_dec0[w * 36864];
    const _Float16* __restrict__ wdeff_w = &g_w_deff[w * 36864];

    _Float16 wo[2][2][4];   // [jj][cc][r] for cells 32w+16cc+4q+r
#pragma unroll
    for (int jj = 0; jj < 2; jj++)
#pragma unroll
        for (int cc = 0; cc < 2; cc++)
#pragma unroll
            for (int r = 0; r < 4; r++)
                wo[jj][cc][r] = g_wout[jj * 256 + 32 * w + 16 * cc + 4 * q + r];

    floatx4 acc[8][4];
    float   c_st[4][2][4];
#pragma unroll
    for (int nt = 0; nt < 4; nt++)
#pragma unroll
        for (int cc = 0; cc < 2; cc++)
#pragma unroll
            for (int r = 0; r < 4; r++) c_st[nt][cc][r] = 0.f;

    __syncthreads();

    int cur = 0;
#pragma unroll 1
    for (int t = 0; t < SEQ + TLEN; t++) {
        const _Float16* __restrict__ Wb =
            (t < SEQ) ? wenc_w : (t == SEQ) ? wdec0_w : wdeff_w;
        const _Float16* __restrict__ hp = h_pack[cur];
        _Float16* __restrict__ hn = h_pack[cur ^ 1];

        // ---- gates = [h|x|1] @ Waug^T ; kt=0 takes literal-zero C ----
#pragma unroll
        for (int kt = 0; kt < 9; kt++) {
            half8 B[4];
#pragma unroll
            for (int nt = 0; nt < 4; nt++)
                B[nt] = *(const half8*)&hp[(nt * 9 + kt) * 512 + aoff];
#pragma unroll
            for (int i = 0; i < 8; i++) {
                half8 Aw = *(const half8*)&Wb[(kt * 8 + i) * 512 + aoff];
                if (kt == 0) {
#pragma unroll
                    for (int nt = 0; nt < 4; nt++)
                        acc[i][nt] = __builtin_amdgcn_mfma_f32_16x16x32_f16(
                            Aw, B[nt], (floatx4)(0.f), 0, 0, 0);
                } else {
#pragma unroll
                    for (int nt = 0; nt < 4; nt++)
                        acc[i][nt] = __builtin_amdgcn_mfma_f32_16x16x32_f16(
                            Aw, B[nt], acc[i][nt], 0, 0, 0);
                }
            }
        }

        float xval = 0.f;
        if (t < SEQ && tid < 128) {
            int srct = (t + 1 < SEQ) ? t + 1 : SEQ - 1;
            xval = x_input[(long)srct * 32768 + (row0 + (tid >> 1)) * 2 + (tid & 1)];
        }

        // ---- elementwise LSTM (preacts pre-scaled by log2e / 2log2e) ----
        const bool dec = (t >= SEQ);
        float po[4][2];
#pragma unroll
        for (int nt = 0; nt < 4; nt++) { po[nt][0] = 0.f; po[nt][1] = 0.f; }

#pragma unroll
        for (int nt = 0; nt < 4; nt++)
#pragma unroll
            for (int cc = 0; cc < 2; cc++) {
                half4 hv4;
                float hvf[4];
#pragma unroll
                for (int r = 0; r < 4; r++) {
                    float ai = acc[cc * 4 + 0][nt][r];
                    float af = acc[cc * 4 + 1][nt][r];
                    float ag = acc[cc * 4 + 2][nt][r];
                    float ao = acc[cc * 4 + 3][nt][r];
                    float eI = __builtin_amdgcn_exp2f(-ai);
                    float eG = __builtin_amdgcn_exp2f(-ag);
                    float eF = __builtin_amdgcn_exp2f(-af);
                    float eO = __builtin_amdgcn_exp2f(-ao);
                    float ig = (1.f - eG) *
                        __builtin_amdgcn_rcpf((1.f + eI) * (1.f + eG));
                    float fs = __builtin_amdgcn_rcpf(1.f + eF);
                    float cn = fmaf(fs, c_st[nt][cc][r], ig);
                    c_st[nt][cc][r] = cn;
                    float cnc = fminf(fmaxf(cn, -12.f), 12.f);
                    float eC = __builtin_amdgcn_exp2f(-LOG2E2 * cnc);
                    float hv = (1.f - eC) *
                        __builtin_amdgcn_rcpf((1.f + eO) * (1.f + eC));
                    hvf[r] = hv;
                    hv4[r] = (_Float16)hv;
                }
                *(half4*)&hn[(nt * 9 + w) * 512 + (2 * cc + (q >> 1)) * 128 +
                             l16 * 8 + 4 * (q & 1)] = hv4;
                if (dec) {
#pragma unroll
                    for (int r = 0; r < 4; r++) {
                        po[nt][0] = fmaf(hvf[r], (float)wo[0][cc][r], po[nt][0]);
                        po[nt][1] = fmaf(hvf[r], (float)wo[1][cc][r], po[nt][1]);
                    }
                }
            }

        if (dec) {
#pragma unroll
            for (int nt = 0; nt < 4; nt++)
#pragma unroll
                for (int jj = 0; jj < 2; jj++) {
                    float s = po[nt][jj];
                    s += __shfl_xor(s, 16);
                    s += __shfl_xor(s, 32);
                    po[nt][jj] = s;
                }
            if (q == 0) {
                float* pl = &partial_lds[t & 1][w * 132];
#pragma unroll
                for (int nt = 0; nt < 4; nt++) {
                    pl[nt * 16 + l16]      = po[nt][0];
                    pl[66 + nt * 16 + l16] = po[nt][1];
                }
            }
        }

        if (t < SEQ && tid < 128) {
            int b = tid >> 1, jj = tid & 1;
            hn[((b >> 4) * 9 + 8) * 512 + (b & 15) * 8 + jj] = (_Float16)xval;
        }

        __syncthreads();   // hn + partials complete

        if (dec && tid < 128) {
            int m = tid >> 1, jj = tid & 1;
            const float* pl = &partial_lds[t & 1][jj * 66 + m];
            float s = bo;
#pragma unroll
            for (int w8 = 0; w8 < 8; w8++) s += pl[w8 * 132];
            out[(long)(t - SEQ) * 32768 + (row0 + m) * 2 + jj] = s;
        }

        cur ^= 1;
    }
}

extern "C" void kernel_launch(void* const* d_in, const int* in_sizes, int n_in,
                              void* d_out, int out_size, void* d_ws, size_t ws_size,
                              hipStream_t stream) {
    (void)in_sizes; (void)n_in; (void)d_ws; (void)ws_size; (void)out_size;
    const float* x      = (const float*)d_in[0];
    const float* W_emb  = (const float*)d_in[1];
    const float* b_emb  = (const float*)d_in[2];
    const float* W_ih_e = (const float*)d_in[3];
    const float* W_hh_e = (const float*)d_in[4];
    const float* b_enc  = (const float*)d_in[5];
    const float* W_ih_d = (const float*)d_in[6];
    const float* W_hh_d = (const float*)d_in[7];
    const float* b_dec  = (const float*)d_in[8];
    const float* W_out  = (const float*)d_in[9];
    const float* b_out  = (const float*)d_in[10];
    float* outp = (float*)d_out;

    prep_kernel<<<512, 256, 0, stream>>>(W_emb, b_emb, W_ih_e, W_hh_e, b_enc,
                                         W_ih_d, W_hh_d, b_dec, W_out, b_out);
    lstm_fused<<<256, 512, 0, stream>>>(x, b_out, outp);
}